// Round 17
// baseline (642.918 us; speedup 1.0000x reference)
//
#include <hip/hip_runtime.h>
#include <hip/hip_cooperative_groups.h>

namespace cg = cooperative_groups;

// ---- fast-path geometry ----
#define NWG  1024               // cooperative grid blocks (4/CU x 256 CU)
#define NBUK 16                 // max batches
#define NQ   4                  // node-quarters per batch
#define QSH  10                 // 1024 nodes per quarter
#define NBUCK 64                // buckets = 16 x 4 (fixed; empties harmless)
#define MAXN 4096               // max nodes/batch
#define SCAN_N (NBUCK * NWG)    // 65536 ghist entries
#define MAXPPB 32               // accum slices per bucket

__global__ __launch_bounds__(256, 4)
void mega_kernel(const float* __restrict__ rel,
                 const float* __restrict__ basis,
                 const float* __restrict__ shifts,
                 const int* __restrict__ src,
                 const int* __restrict__ dst,
                 const int* __restrict__ bch,
                 const float* __restrict__ raw,
                 float* __restrict__ out,
                 float4* __restrict__ pos4,
                 int* __restrict__ ghist,
                 int* __restrict__ bsums,
                 float4* __restrict__ recs,
                 float* __restrict__ partials,
                 int BN, int N, int E, int chunk, int PPB) {
    cg::grid_group grid = cg::this_grid();
    __shared__ float acc[(1 << QSH) * 3];   // 12 KB, aliased by early phases
    int* h   = (int*)acc;                   // [NBUCK]
    int* cur = (int*)acc + NBUCK;           // [NBUCK]
    int* tp  = (int*)acc + 2 * NBUCK;       // [256] scan temp
    int blk = blockIdx.x, tid = threadIdx.x;

    // ---- Phase A: pos4 = rel@basis (blocks covering BN) + per-block bucket hist ----
    for (int idx = blk * 256 + tid; idx < BN; idx += NWG * 256) {
        int b = idx / N;
        const float* bm = basis + b * 9;
        float x = rel[idx * 3 + 0], y = rel[idx * 3 + 1], z = rel[idx * 3 + 2];
        float4 p;
        p.x = x * bm[0] + y * bm[3] + z * bm[6];
        p.y = x * bm[1] + y * bm[4] + z * bm[7];
        p.z = x * bm[2] + y * bm[5] + z * bm[8];
        p.w = 0.0f;
        pos4[idx] = p;
    }
    if (tid < NBUCK) h[tid] = 0;
    __syncthreads();
    int lo = blk * chunk, hi = min(E, lo + chunk);
    for (int e0 = lo + tid * 8; e0 < hi; e0 += 2048) {
        if (e0 + 7 < hi) {
            int4 bA = *(const int4*)(bch + e0);
            int4 bB = *(const int4*)(bch + e0 + 4);
            int4 sA = *(const int4*)(src + e0);
            int4 sB = *(const int4*)(src + e0 + 4);
            atomicAdd(&h[bA.x * NQ + (sA.x >> QSH)], 1);
            atomicAdd(&h[bA.y * NQ + (sA.y >> QSH)], 1);
            atomicAdd(&h[bA.z * NQ + (sA.z >> QSH)], 1);
            atomicAdd(&h[bA.w * NQ + (sA.w >> QSH)], 1);
            atomicAdd(&h[bB.x * NQ + (sB.x >> QSH)], 1);
            atomicAdd(&h[bB.y * NQ + (sB.y >> QSH)], 1);
            atomicAdd(&h[bB.z * NQ + (sB.z >> QSH)], 1);
            atomicAdd(&h[bB.w * NQ + (sB.w >> QSH)], 1);
        } else {
            for (int e = e0; e < hi; ++e)
                atomicAdd(&h[bch[e] * NQ + (src[e] >> QSH)], 1);
        }
    }
    __syncthreads();
    if (tid < NBUCK) ghist[tid * NWG + blk] = h[tid];

    grid.sync();

    // ---- Phase B1: scan 64 tiles of 1024 entries (blocks 0..63) ----
    if (blk < SCAN_N / 1024) {
        int base = blk * 1024 + tid * 4;
        int v0 = ghist[base], v1 = ghist[base + 1], v2 = ghist[base + 2], v3 = ghist[base + 3];
        int s = v0 + v1 + v2 + v3;
        tp[tid] = s;
        for (int off = 1; off < 256; off <<= 1) {
            __syncthreads();
            int t = (tid >= off) ? tp[tid - off] : 0;
            __syncthreads();
            tp[tid] += t;
        }
        __syncthreads();
        int incl = tp[tid];
        int excl = incl - s;
        ghist[base]     = excl;
        ghist[base + 1] = excl + v0;
        ghist[base + 2] = excl + v0 + v1;
        ghist[base + 3] = excl + v0 + v1 + v2;
        if (tid == 255) bsums[blk] = incl;
    }

    grid.sync();

    // ---- Phase B2: block 0 exclusive-scans bsums[64] ----
    if (blk == 0) {
        int v = (tid < SCAN_N / 1024) ? bsums[tid] : 0;
        tp[tid] = v;
        for (int off = 1; off < 256; off <<= 1) {
            __syncthreads();
            int t = (tid >= off) ? tp[tid - off] : 0;
            __syncthreads();
            tp[tid] += t;
        }
        __syncthreads();
        if (tid < SCAN_N / 1024) bsums[tid] = tp[tid] - v;
    }

    grid.sync();

    // ---- Phase C: scatter records grouped by bucket ----
    if (tid < NBUCK) {
        int idx = tid * NWG + blk;
        cur[tid] = ghist[idx] + bsums[idx >> 10];
    }
    __syncthreads();
    for (int e0 = lo + tid * 8; e0 < hi; e0 += 2048) {
        if (e0 + 7 < hi) {
            int4 sA = *(const int4*)(src + e0);
            int4 sB = *(const int4*)(src + e0 + 4);
            int4 dA = *(const int4*)(dst + e0);
            int4 dB = *(const int4*)(dst + e0 + 4);
            int4 bA = *(const int4*)(bch + e0);
            int4 bB = *(const int4*)(bch + e0 + 4);
            const float4* sh4 = (const float4*)(shifts + (size_t)e0 * 3);
            float4 F0 = sh4[0], F1 = sh4[1], F2 = sh4[2];
            float4 F3 = sh4[3], F4 = sh4[4], F5 = sh4[5];
            int se[8] = {sA.x, sA.y, sA.z, sA.w, sB.x, sB.y, sB.z, sB.w};
            int de[8] = {dA.x, dA.y, dA.z, dA.w, dB.x, dB.y, dB.z, dB.w};
            int be[8] = {bA.x, bA.y, bA.z, bA.w, bB.x, bB.y, bB.z, bB.w};
            float sx[8] = {F0.x, F0.w, F1.z, F2.y, F3.x, F3.w, F4.z, F5.y};
            float sy[8] = {F0.y, F1.x, F1.w, F2.z, F3.y, F4.x, F4.w, F5.z};
            float sz[8] = {F0.z, F1.y, F2.x, F2.w, F3.z, F4.y, F5.x, F5.w};
#pragma unroll
            for (int k = 0; k < 8; ++k) {
                int slot = atomicAdd(&cur[be[k] * NQ + (se[k] >> QSH)], 1);
                float4 rec;
                rec.x = sx[k]; rec.y = sy[k]; rec.z = sz[k];
                rec.w = __int_as_float(se[k] | (de[k] << 12));
                recs[slot] = rec;
            }
        } else {
            for (int e = e0; e < hi; ++e) {
                int slot = atomicAdd(&cur[bch[e] * NQ + (src[e] >> QSH)], 1);
                float4 rec;
                rec.x = shifts[(size_t)e * 3 + 0];
                rec.y = shifts[(size_t)e * 3 + 1];
                rec.z = shifts[(size_t)e * 3 + 2];
                rec.w = __int_as_float(src[e] | (dst[e] << 12));
                recs[slot] = rec;
            }
        }
    }

    grid.sync();

    // ---- Phase D: accum — 64*PPB virtual slices, grid-stride ----
    for (int vb = blk; vb < NBUCK * PPB; vb += NWG) {
        __syncthreads();
        for (int i = tid * 4; i < (1 << QSH) * 3; i += 1024)
            *(float4*)&acc[i] = make_float4(0.f, 0.f, 0.f, 0.f);
        __syncthreads();
        int bucket = vb / PPB, p = vb - bucket * PPB;
        int b = bucket >> 2;
        int nb = (bucket & 3) << QSH;
        int g0 = bucket * NWG;
        int i0 = ghist[g0] + bsums[g0 >> 10];
        int i1 = E;
        if (bucket + 1 < NBUCK) {
            int g1 = (bucket + 1) * NWG;
            i1 = ghist[g1] + bsums[g1 >> 10];
        }
        const float4* pb = pos4 + (size_t)b * N;
        long long len = (long long)(i1 - i0);
        int slo = i0 + (int)(len * p / PPB);
        int shi = i0 + (int)(len * (p + 1) / PPB);

#define PROC(r)                                                        \
        {                                                              \
            int u = __float_as_int((r).w);                             \
            int s_ = u & 4095, d_ = (u >> 12) & 4095;                  \
            float4 P = pb[d_], Q = pb[s_];                             \
            float dx = P.x - Q.x + (r).x;                              \
            float dy = P.y - Q.y + (r).y;                              \
            float dz = P.z - Q.z + (r).z;                              \
            float rr = sqrtf(dx * dx + dy * dy + dz * dz);             \
            float pref = 2.0f * (rr - 3.0f) / (rr + 1e-8f);            \
            int nl = s_ - nb;                                          \
            atomicAdd(&acc[nl * 3 + 0], pref * dx);                    \
            atomicAdd(&acc[nl * 3 + 1], pref * dy);                    \
            atomicAdd(&acc[nl * 3 + 2], pref * dz);                    \
        }

        int i = slo + tid;
        for (; i + 768 < shi; i += 1024) {
            float4 r0 = recs[i];
            float4 r1 = recs[i + 256];
            float4 r2 = recs[i + 512];
            float4 r3 = recs[i + 768];
            PROC(r0); PROC(r1); PROC(r2); PROC(r3);
        }
        for (; i < shi; i += 256) {
            float4 r = recs[i];
            PROC(r);
        }
#undef PROC
        __syncthreads();
        float* dstp = partials + (size_t)vb * ((1 << QSH) * 3);
        for (int i2 = tid * 4; i2 < (1 << QSH) * 3; i2 += 1024)
            *(float4*)&dstp[i2] = *(const float4*)&acc[i2];
    }

    grid.sync();

    // ---- Phase E: final — sum PPB partials, fold inverse, residual ----
    for (int idx = blk * 256 + tid; idx < BN; idx += NWG * 256) {
        int b = idx / N;
        int n = idx - b * N;
        int q = n >> QSH;
        int nl = n - (q << QSH);
        int bucket = b * NQ + q;
        const int Q3 = (1 << QSH) * 3;
        const float* pp = partials + (size_t)bucket * PPB * Q3 + (size_t)nl * 3;
        float x = 0.f, y = 0.f, z = 0.f;
        for (int p = 0; p < PPB; ++p) {
            x += pp[0]; y += pp[1]; z += pp[2];
            pp += Q3;
        }
        const float* m = basis + b * 9;
        float a00 = m[0], a01 = m[1], a02 = m[2];
        float a10 = m[3], a11 = m[4], a12 = m[5];
        float a20 = m[6], a21 = m[7], a22 = m[8];
        float c00 = a11 * a22 - a12 * a21;
        float c01 = -(a10 * a22 - a12 * a20);
        float c02 = a10 * a21 - a11 * a20;
        float det = a00 * c00 + a01 * c01 + a02 * c02;
        float id = 1.0f / det;
        float rm0 = c00 * id;
        float rm1 = (a02 * a21 - a01 * a22) * id;
        float rm2 = (a01 * a12 - a02 * a11) * id;
        float rm3 = c01 * id;
        float rm4 = (a00 * a22 - a02 * a20) * id;
        float rm5 = (a02 * a10 - a00 * a12) * id;
        float rm6 = c02 * id;
        float rm7 = (a01 * a20 - a00 * a21) * id;
        float rm8 = (a00 * a11 - a01 * a10) * id;
        out[idx * 3 + 0] = raw[idx * 3 + 0] + x * rm0 + y * rm3 + z * rm6;
        out[idx * 3 + 1] = raw[idx * 3 + 1] + x * rm1 + y * rm4 + z * rm7;
        out[idx * 3 + 2] = raw[idx * 3 + 2] + x * rm2 + y * rm5 + z * rm8;
    }
}

// ---------------- fallback (device atomics, known-good ~315 us) ----------------
__global__ void pos3_kernel(const float* __restrict__ rel,
                            const float* __restrict__ basis,
                            float* __restrict__ pos,
                            int BN, int N) {
    int idx = blockIdx.x * blockDim.x + threadIdx.x;
    if (idx >= BN) return;
    int b = idx / N;
    const float* bm = basis + b * 9;
    float x = rel[idx * 3 + 0], y = rel[idx * 3 + 1], z = rel[idx * 3 + 2];
    pos[idx * 3 + 0] = x * bm[0] + y * bm[3] + z * bm[6];
    pos[idx * 3 + 1] = x * bm[1] + y * bm[4] + z * bm[7];
    pos[idx * 3 + 2] = x * bm[2] + y * bm[5] + z * bm[8];
}

__global__ void inv_kernel(const float* __restrict__ basis,
                           float* __restrict__ recip, int B) {
    int b = blockIdx.x * blockDim.x + threadIdx.x;
    if (b >= B) return;
    const float* m = basis + b * 9;
    float a00 = m[0], a01 = m[1], a02 = m[2];
    float a10 = m[3], a11 = m[4], a12 = m[5];
    float a20 = m[6], a21 = m[7], a22 = m[8];
    float c00 = a11 * a22 - a12 * a21;
    float c01 = -(a10 * a22 - a12 * a20);
    float c02 = a10 * a21 - a11 * a20;
    float det = a00 * c00 + a01 * c01 + a02 * c02;
    float id = 1.0f / det;
    float* r = recip + b * 9;
    r[0] = c00 * id;
    r[1] = (a02 * a21 - a01 * a22) * id;
    r[2] = (a01 * a12 - a02 * a11) * id;
    r[3] = c01 * id;
    r[4] = (a00 * a22 - a02 * a20) * id;
    r[5] = (a02 * a10 - a00 * a12) * id;
    r[6] = c02 * id;
    r[7] = (a01 * a20 - a00 * a21) * id;
    r[8] = (a00 * a11 - a01 * a10) * id;
}

__global__ void edge_kernel_dev(const float* __restrict__ pos,
                                const float* __restrict__ shifts,
                                const int* __restrict__ src,
                                const int* __restrict__ dst,
                                const int* __restrict__ bch,
                                float* __restrict__ cart,
                                int E, int N) {
    int e = blockIdx.x * blockDim.x + threadIdx.x;
    if (e >= E) return;
    int b = bch[e], s = src[e], d = dst[e];
    int base = b * N;
    const float* pd = pos + (size_t)(base + d) * 3;
    const float* ps = pos + (size_t)(base + s) * 3;
    float dx = pd[0] - ps[0] + shifts[(size_t)e * 3 + 0];
    float dy = pd[1] - ps[1] + shifts[(size_t)e * 3 + 1];
    float dz = pd[2] - ps[2] + shifts[(size_t)e * 3 + 2];
    float r = sqrtf(dx * dx + dy * dy + dz * dz);
    float pref = 2.0f * (r - 3.0f) / (r + 1e-8f);
    float* c = cart + (size_t)(base + s) * 3;
    atomicAdd(&c[0], pref * dx);
    atomicAdd(&c[1], pref * dy);
    atomicAdd(&c[2], pref * dz);
}

__global__ void out_kernel(const float* __restrict__ cart,
                           const float* __restrict__ recip,
                           const float* __restrict__ raw,
                           float* __restrict__ out,
                           int BN, int N) {
    int idx = blockIdx.x * blockDim.x + threadIdx.x;
    if (idx >= BN) return;
    int b = idx / N;
    const float* rm = recip + b * 9;
    float x = cart[idx * 3 + 0], y = cart[idx * 3 + 1], z = cart[idx * 3 + 2];
    out[idx * 3 + 0] = raw[idx * 3 + 0] + x * rm[0] + y * rm[3] + z * rm[6];
    out[idx * 3 + 1] = raw[idx * 3 + 1] + x * rm[1] + y * rm[4] + z * rm[7];
    out[idx * 3 + 2] = raw[idx * 3 + 2] + x * rm[2] + y * rm[5] + z * rm[8];
}

extern "C" void kernel_launch(void* const* d_in, const int* in_sizes, int n_in,
                              void* d_out, int out_size, void* d_ws, size_t ws_size,
                              hipStream_t stream) {
    const float* rel    = (const float*)d_in[0];
    const float* basis  = (const float*)d_in[1];
    const float* shifts = (const float*)d_in[2];
    const float* raw    = (const float*)d_in[3];
    const int*   src    = (const int*)d_in[4];
    const int*   dst    = (const int*)d_in[5];
    const int*   bch    = (const int*)d_in[6];

    int B  = in_sizes[1] / 9;
    int BN = in_sizes[0] / 3;
    int N  = BN / B;
    int E  = in_sizes[4];

    // ws layout: recs[E] f4 | pos4[BN] f4 | ghist[SCAN_N] i32 | bsums[64] i32 | partials
    char* w = (char*)d_ws;
    float4* recs  = (float4*)w;  w += (size_t)E * 16;
    float4* pos4  = (float4*)w;  w += (size_t)BN * 16;
    int*    ghist = (int*)w;     w += (size_t)SCAN_N * 4;
    int*    bsums = (int*)w;     w += 64 * 4;
    float*  partials = (float*)w;
    size_t base_bytes = (size_t)(w - (char*)d_ws);

    bool geom_ok = (B >= 1) && (B <= NBUK) && (N >= 4) && (N <= MAXN) &&
                   (BN == B * N) && (E >= 8);
    size_t per_ppb = (size_t)NBUCK * (1 << QSH) * 3 * 4;  // one slice over 64 buckets
    int PPB = 0;
    if (geom_ok && ws_size > base_bytes)
        PPB = (int)((ws_size - base_bytes) / per_ppb);
    if (PPB > MAXPPB) PPB = MAXPPB;

    int dev = 0, coop = 0;
    hipGetDevice(&dev);
    hipDeviceGetAttribute(&coop, hipDeviceAttributeCooperativeLaunch, dev);

    if (geom_ok && PPB >= 2 && coop) {
        int chunk = ((E + NWG - 1) / NWG + 7) & ~7;
        float* outp = (float*)d_out;
        void* args[] = {
            (void*)&rel, (void*)&basis, (void*)&shifts,
            (void*)&src, (void*)&dst, (void*)&bch,
            (void*)&raw, (void*)&outp,
            (void*)&pos4, (void*)&ghist, (void*)&bsums, (void*)&recs, (void*)&partials,
            (void*)&BN, (void*)&N, (void*)&E, (void*)&chunk, (void*)&PPB
        };
        hipLaunchCooperativeKernel((const void*)mega_kernel, dim3(NWG), dim3(256),
                                   args, 0, stream);
    } else {
        // fallback: device-scope atomics
        float* pos  = (float*)d_ws;
        float* cart = pos + (size_t)BN * 3;
        float* rcp  = cart + (size_t)BN * 3;
        hipMemsetAsync(cart, 0, (size_t)BN * 3 * sizeof(float), stream);
        pos3_kernel<<<(BN + 255) / 256, 256, 0, stream>>>(rel, basis, pos, BN, N);
        inv_kernel<<<1, 64, 0, stream>>>(basis, rcp, B);
        edge_kernel_dev<<<(E + 255) / 256, 256, 0, stream>>>(pos, shifts, src, dst, bch,
                                                             cart, E, N);
        out_kernel<<<(BN + 255) / 256, 256, 0, stream>>>(cart, rcp, raw,
                                                         (float*)d_out, BN, N);
    }
}

// Round 18
// 73.003 us; speedup vs baseline: 8.8068x; 8.8068x over previous
//
#include <hip/hip_runtime.h>

// ---- fast-path geometry ----
#define NBLK 1024               // hist/scatter blocks (8 edges/thread)
#define NBUK 16                 // max batches
#define NQ   4                  // node-quarters per batch
#define QSH  10                 // 1024 nodes per quarter
#define NBUCK (NBUK * NQ)       // 64 buckets
#define MAXN 4096               // max nodes/batch (NQ << QSH)
#define SCAN_N (NBUCK * NBLK)   // 65536 ghist entries
#define SCAN_BS 1024
#define MAXPPB 16               // accum slices per bucket (grid 1024 = 4/CU resident)

// K1: blocks [0,PB): pos4[idx] = rel@basis; blocks [PB,PB+NBLK): (batch,quarter) histogram
__global__ void prep_kernel(const float* __restrict__ rel,
                            const float* __restrict__ basis,
                            const int* __restrict__ src,
                            const int* __restrict__ bch,
                            float4* __restrict__ pos4,
                            int* __restrict__ ghist,
                            int BN, int N, int E, int chunk, int PB) {
    int blk = blockIdx.x, tid = threadIdx.x;
    if (blk < PB) {
        int idx = blk * 256 + tid;
        if (idx < BN) {
            int b = idx / N;
            const float* bm = basis + b * 9;
            float x = rel[idx * 3 + 0], y = rel[idx * 3 + 1], z = rel[idx * 3 + 2];
            float4 p;
            p.x = x * bm[0] + y * bm[3] + z * bm[6];
            p.y = x * bm[1] + y * bm[4] + z * bm[7];
            p.z = x * bm[2] + y * bm[5] + z * bm[8];
            p.w = 0.0f;
            pos4[idx] = p;
        }
        return;
    }
    __shared__ int h[NBUCK];
    int hb = blk - PB;
    if (tid < NBUCK) h[tid] = 0;
    __syncthreads();
    int lo = hb * chunk, hi = min(E, lo + chunk);
    for (int e0 = lo + tid * 8; e0 < hi; e0 += 2048) {
        if (e0 + 7 < hi) {
            int4 bA = *(const int4*)(bch + e0);
            int4 bB = *(const int4*)(bch + e0 + 4);
            int4 sA = *(const int4*)(src + e0);
            int4 sB = *(const int4*)(src + e0 + 4);
            atomicAdd(&h[bA.x * NQ + (sA.x >> QSH)], 1);
            atomicAdd(&h[bA.y * NQ + (sA.y >> QSH)], 1);
            atomicAdd(&h[bA.z * NQ + (sA.z >> QSH)], 1);
            atomicAdd(&h[bA.w * NQ + (sA.w >> QSH)], 1);
            atomicAdd(&h[bB.x * NQ + (sB.x >> QSH)], 1);
            atomicAdd(&h[bB.y * NQ + (sB.y >> QSH)], 1);
            atomicAdd(&h[bB.z * NQ + (sB.z >> QSH)], 1);
            atomicAdd(&h[bB.w * NQ + (sB.w >> QSH)], 1);
        } else {
            for (int e = e0; e < hi; ++e)
                atomicAdd(&h[bch[e] * NQ + (src[e] >> QSH)], 1);
        }
    }
    __syncthreads();
    if (tid < NBUCK) ghist[tid * NBLK + hb] = h[tid];
}

// K2a: scan 1024-element tiles (exclusive, in place), emit tile sums (64 tiles)
__global__ void scan1_kernel(int* __restrict__ g, int* __restrict__ bsums) {
    __shared__ int tp[256];
    int tid = threadIdx.x;
    int base = blockIdx.x * SCAN_BS + tid * 4;
    int v0 = g[base], v1 = g[base + 1], v2 = g[base + 2], v3 = g[base + 3];
    int s = v0 + v1 + v2 + v3;
    tp[tid] = s;
    for (int off = 1; off < 256; off <<= 1) {
        __syncthreads();
        int t = (tid >= off) ? tp[tid - off] : 0;
        __syncthreads();
        tp[tid] += t;
    }
    __syncthreads();
    int incl = tp[tid];
    int excl = incl - s;
    g[base]     = excl;
    g[base + 1] = excl + v0;
    g[base + 2] = excl + v0 + v1;
    g[base + 3] = excl + v0 + v1 + v2;
    if (tid == 255) bsums[blockIdx.x] = incl;
}

// K2b: exclusive scan of tile sums (n <= 1024), one block
__global__ void scan2_kernel(int* __restrict__ bsums, int n) {
    __shared__ int tp[1024];
    int tid = threadIdx.x;
    int v = (tid < n) ? bsums[tid] : 0;
    tp[tid] = v;
    for (int off = 1; off < 1024; off <<= 1) {
        __syncthreads();
        int t = (tid >= off) ? tp[tid - off] : 0;
        __syncthreads();
        tp[tid] += t;
    }
    __syncthreads();
    if (tid < n) bsums[tid] = tp[tid] - v;
}

// K3: pure reorder — record = (shift.xyz, src|dst<<12) grouped by (batch,quarter) bucket.
__global__ void scatter_kernel(const float* __restrict__ shifts,
                               const int* __restrict__ src,
                               const int* __restrict__ dst,
                               const int* __restrict__ bch,
                               const int* __restrict__ ghist,
                               const int* __restrict__ bsums,
                               float4* __restrict__ recs,
                               int E, int chunk) {
    __shared__ int cur[NBUCK];
    int tid = threadIdx.x, blk = blockIdx.x;
    if (tid < NBUCK) {
        int idx = tid * NBLK + blk;
        cur[tid] = ghist[idx] + bsums[idx >> 10];
    }
    __syncthreads();
    int lo = blk * chunk, hi = min(E, lo + chunk);
    for (int e0 = lo + tid * 8; e0 < hi; e0 += 2048) {
        if (e0 + 7 < hi) {
            int4 sA = *(const int4*)(src + e0);
            int4 sB = *(const int4*)(src + e0 + 4);
            int4 dA = *(const int4*)(dst + e0);
            int4 dB = *(const int4*)(dst + e0 + 4);
            int4 bA = *(const int4*)(bch + e0);
            int4 bB = *(const int4*)(bch + e0 + 4);
            const float4* sh4 = (const float4*)(shifts + (size_t)e0 * 3);
            float4 F0 = sh4[0], F1 = sh4[1], F2 = sh4[2];
            float4 F3 = sh4[3], F4 = sh4[4], F5 = sh4[5];
            int se[8] = {sA.x, sA.y, sA.z, sA.w, sB.x, sB.y, sB.z, sB.w};
            int de[8] = {dA.x, dA.y, dA.z, dA.w, dB.x, dB.y, dB.z, dB.w};
            int be[8] = {bA.x, bA.y, bA.z, bA.w, bB.x, bB.y, bB.z, bB.w};
            float sx[8] = {F0.x, F0.w, F1.z, F2.y, F3.x, F3.w, F4.z, F5.y};
            float sy[8] = {F0.y, F1.x, F1.w, F2.z, F3.y, F4.x, F4.w, F5.z};
            float sz[8] = {F0.z, F1.y, F2.x, F2.w, F3.z, F4.y, F5.x, F5.w};
#pragma unroll
            for (int k = 0; k < 8; ++k) {
                int slot = atomicAdd(&cur[be[k] * NQ + (se[k] >> QSH)], 1);
                float4 rec;
                rec.x = sx[k]; rec.y = sy[k]; rec.z = sz[k];
                rec.w = __int_as_float(se[k] | (de[k] << 12));
                recs[slot] = rec;
            }
        } else {
            for (int e = e0; e < hi; ++e) {
                int slot = atomicAdd(&cur[bch[e] * NQ + (src[e] >> QSH)], 1);
                float4 rec;
                rec.x = shifts[(size_t)e * 3 + 0];
                rec.y = shifts[(size_t)e * 3 + 1];
                rec.z = shifts[(size_t)e * 3 + 2];
                rec.w = __int_as_float(src[e] | (dst[e] << 12));
                recs[slot] = rec;
            }
        }
    }
}

// K4: per (bucket, slice): 12 KB LDS accumulator (1024 nodes), global pos gathers (L2-hot).
__global__ __launch_bounds__(256, 4)
void accum_kernel(const float4* __restrict__ recs,
                  const float4* __restrict__ pos4,
                  const int* __restrict__ ghist,
                  const int* __restrict__ bsums,
                  float* __restrict__ partials,
                  int E, int N, int PPB) {
    __shared__ float acc[(1 << QSH) * 3];  // 12 KB
    int bx = blockIdx.x;
    int bucket = bx / PPB, p = bx - bucket * PPB;
    int b = bucket >> 2, q = bucket & 3;   // NQ == 4
    int nb = q << QSH;
    int tid = threadIdx.x;
    for (int i = tid * 4; i < (1 << QSH) * 3; i += 1024)
        *(float4*)&acc[i] = make_float4(0.f, 0.f, 0.f, 0.f);
    __syncthreads();
    int g0 = bucket * NBLK;
    int i0 = ghist[g0] + bsums[g0 >> 10];
    int i1 = E;
    if (bucket + 1 < NBUCK) {
        int g1 = (bucket + 1) * NBLK;
        i1 = ghist[g1] + bsums[g1 >> 10];
    }
    const float4* pb = pos4 + (size_t)b * N;
    long long len = (long long)(i1 - i0);
    int lo = i0 + (int)(len * p / PPB);
    int hi = i0 + (int)(len * (p + 1) / PPB);

#define PROC(r)                                                        \
    {                                                                  \
        int u = __float_as_int((r).w);                                 \
        int s_ = u & 4095, d_ = (u >> 12) & 4095;                      \
        float4 P = pb[d_], Q = pb[s_];                                 \
        float dx = P.x - Q.x + (r).x;                                  \
        float dy = P.y - Q.y + (r).y;                                  \
        float dz = P.z - Q.z + (r).z;                                  \
        float rr = sqrtf(dx * dx + dy * dy + dz * dz);                 \
        float pref = 2.0f * (rr - 3.0f) / (rr + 1e-8f);                \
        int nl = s_ - nb;                                              \
        atomicAdd(&acc[nl * 3 + 0], pref * dx);                        \
        atomicAdd(&acc[nl * 3 + 1], pref * dy);                        \
        atomicAdd(&acc[nl * 3 + 2], pref * dz);                        \
    }

    int i = lo + tid;
    for (; i + 768 < hi; i += 1024) {
        float4 r0 = recs[i];
        float4 r1 = recs[i + 256];
        float4 r2 = recs[i + 512];
        float4 r3 = recs[i + 768];
        PROC(r0); PROC(r1); PROC(r2); PROC(r3);
    }
    for (; i < hi; i += 256) {
        float4 r = recs[i];
        PROC(r);
    }
#undef PROC
    __syncthreads();
    float* dstp = partials + (size_t)bx * ((1 << QSH) * 3);
    for (int i2 = tid * 4; i2 < (1 << QSH) * 3; i2 += 1024)
        *(float4*)&dstp[i2] = *(const float4*)&acc[i2];
}

// K5: sum PPB partials per node, fold 3x3 inverse, transform + residual
__global__ void final_kernel(const float* __restrict__ partials,
                             const float* __restrict__ basis,
                             const float* __restrict__ raw,
                             float* __restrict__ out,
                             int BN, int N, int PPB) {
    int idx = blockIdx.x * blockDim.x + threadIdx.x;
    if (idx >= BN) return;
    int b = idx / N;
    int n = idx - b * N;
    int q = n >> QSH;
    int nl = n - (q << QSH);
    int bucket = b * NQ + q;
    const int Q3 = (1 << QSH) * 3;
    const float* pp = partials + (size_t)bucket * PPB * Q3 + (size_t)nl * 3;
    float x = 0.f, y = 0.f, z = 0.f;
    for (int p = 0; p < PPB; ++p) {
        x += pp[0]; y += pp[1]; z += pp[2];
        pp += Q3;
    }
    const float* m = basis + b * 9;
    float a00 = m[0], a01 = m[1], a02 = m[2];
    float a10 = m[3], a11 = m[4], a12 = m[5];
    float a20 = m[6], a21 = m[7], a22 = m[8];
    float c00 = a11 * a22 - a12 * a21;
    float c01 = -(a10 * a22 - a12 * a20);
    float c02 = a10 * a21 - a11 * a20;
    float det = a00 * c00 + a01 * c01 + a02 * c02;
    float id = 1.0f / det;
    float rm0 = c00 * id;
    float rm1 = (a02 * a21 - a01 * a22) * id;
    float rm2 = (a01 * a12 - a02 * a11) * id;
    float rm3 = c01 * id;
    float rm4 = (a00 * a22 - a02 * a20) * id;
    float rm5 = (a02 * a10 - a00 * a12) * id;
    float rm6 = c02 * id;
    float rm7 = (a01 * a20 - a00 * a21) * id;
    float rm8 = (a00 * a11 - a01 * a10) * id;
    out[idx * 3 + 0] = raw[idx * 3 + 0] + x * rm0 + y * rm3 + z * rm6;
    out[idx * 3 + 1] = raw[idx * 3 + 1] + x * rm1 + y * rm4 + z * rm7;
    out[idx * 3 + 2] = raw[idx * 3 + 2] + x * rm2 + y * rm5 + z * rm8;
}

// ---------------- fallback (device atomics, known-good ~315 us) ----------------
__global__ void pos3_kernel(const float* __restrict__ rel,
                            const float* __restrict__ basis,
                            float* __restrict__ pos,
                            int BN, int N) {
    int idx = blockIdx.x * blockDim.x + threadIdx.x;
    if (idx >= BN) return;
    int b = idx / N;
    const float* bm = basis + b * 9;
    float x = rel[idx * 3 + 0], y = rel[idx * 3 + 1], z = rel[idx * 3 + 2];
    pos[idx * 3 + 0] = x * bm[0] + y * bm[3] + z * bm[6];
    pos[idx * 3 + 1] = x * bm[1] + y * bm[4] + z * bm[7];
    pos[idx * 3 + 2] = x * bm[2] + y * bm[5] + z * bm[8];
}

__global__ void inv_kernel(const float* __restrict__ basis,
                           float* __restrict__ recip, int B) {
    int b = blockIdx.x * blockDim.x + threadIdx.x;
    if (b >= B) return;
    const float* m = basis + b * 9;
    float a00 = m[0], a01 = m[1], a02 = m[2];
    float a10 = m[3], a11 = m[4], a12 = m[5];
    float a20 = m[6], a21 = m[7], a22 = m[8];
    float c00 = a11 * a22 - a12 * a21;
    float c01 = -(a10 * a22 - a12 * a20);
    float c02 = a10 * a21 - a11 * a20;
    float det = a00 * c00 + a01 * c01 + a02 * c02;
    float id = 1.0f / det;
    float* r = recip + b * 9;
    r[0] = c00 * id;
    r[1] = (a02 * a21 - a01 * a22) * id;
    r[2] = (a01 * a12 - a02 * a11) * id;
    r[3] = c01 * id;
    r[4] = (a00 * a22 - a02 * a20) * id;
    r[5] = (a02 * a10 - a00 * a12) * id;
    r[6] = c02 * id;
    r[7] = (a01 * a20 - a00 * a21) * id;
    r[8] = (a00 * a11 - a01 * a10) * id;
}

__global__ void edge_kernel_dev(const float* __restrict__ pos,
                                const float* __restrict__ shifts,
                                const int* __restrict__ src,
                                const int* __restrict__ dst,
                                const int* __restrict__ bch,
                                float* __restrict__ cart,
                                int E, int N) {
    int e = blockIdx.x * blockDim.x + threadIdx.x;
    if (e >= E) return;
    int b = bch[e], s = src[e], d = dst[e];
    int base = b * N;
    const float* pd = pos + (size_t)(base + d) * 3;
    const float* ps = pos + (size_t)(base + s) * 3;
    float dx = pd[0] - ps[0] + shifts[(size_t)e * 3 + 0];
    float dy = pd[1] - ps[1] + shifts[(size_t)e * 3 + 1];
    float dz = pd[2] - ps[2] + shifts[(size_t)e * 3 + 2];
    float r = sqrtf(dx * dx + dy * dy + dz * dz);
    float pref = 2.0f * (r - 3.0f) / (r + 1e-8f);
    float* c = cart + (size_t)(base + s) * 3;
    atomicAdd(&c[0], pref * dx);
    atomicAdd(&c[1], pref * dy);
    atomicAdd(&c[2], pref * dz);
}

__global__ void out_kernel(const float* __restrict__ cart,
                           const float* __restrict__ recip,
                           const float* __restrict__ raw,
                           float* __restrict__ out,
                           int BN, int N) {
    int idx = blockIdx.x * blockDim.x + threadIdx.x;
    if (idx >= BN) return;
    int b = idx / N;
    const float* rm = recip + b * 9;
    float x = cart[idx * 3 + 0], y = cart[idx * 3 + 1], z = cart[idx * 3 + 2];
    out[idx * 3 + 0] = raw[idx * 3 + 0] + x * rm[0] + y * rm[3] + z * rm[6];
    out[idx * 3 + 1] = raw[idx * 3 + 1] + x * rm[1] + y * rm[4] + z * rm[7];
    out[idx * 3 + 2] = raw[idx * 3 + 2] + x * rm[2] + y * rm[5] + z * rm[8];
}

extern "C" void kernel_launch(void* const* d_in, const int* in_sizes, int n_in,
                              void* d_out, int out_size, void* d_ws, size_t ws_size,
                              hipStream_t stream) {
    const float* rel    = (const float*)d_in[0];
    const float* basis  = (const float*)d_in[1];
    const float* shifts = (const float*)d_in[2];
    const float* raw    = (const float*)d_in[3];
    const int*   src    = (const int*)d_in[4];
    const int*   dst    = (const int*)d_in[5];
    const int*   bch    = (const int*)d_in[6];

    int B  = in_sizes[1] / 9;
    int BN = in_sizes[0] / 3;
    int N  = BN / B;
    int E  = in_sizes[4];

    // ws layout: recs[E] f4 | pos4[BN] f4 | ghist[SCAN_N] i32 | bsums[1024] i32 | partials
    char* w = (char*)d_ws;
    float4* recs  = (float4*)w;  w += (size_t)E * 16;
    float4* pos4  = (float4*)w;  w += (size_t)BN * 16;
    int*    ghist = (int*)w;     w += (size_t)SCAN_N * 4;
    int*    bsums = (int*)w;     w += 1024 * 4;
    float*  partials = (float*)w;
    size_t base_bytes = (size_t)(w - (char*)d_ws);

    bool geom_ok = (B >= 1) && (B <= NBUK) && (N >= 4) && (N <= MAXN) &&
                   (BN == B * N) && (E >= 8);
    size_t per_ppb = (size_t)B * NQ * (1 << QSH) * 3 * 4;  // one slice across all buckets
    int PPB = 0;
    if (geom_ok && ws_size > base_bytes)
        PPB = (int)((ws_size - base_bytes) / per_ppb);
    if (PPB > MAXPPB) PPB = MAXPPB;

    if (geom_ok && PPB >= 2) {
        // chunk: multiple of 8 so int4 pairs stay aligned
        int chunk = ((E + NBLK - 1) / NBLK + 7) & ~7;
        int PB = (BN + 255) / 256;
        prep_kernel<<<PB + NBLK, 256, 0, stream>>>(rel, basis, src, bch, pos4, ghist,
                                                   BN, N, E, chunk, PB);
        scan1_kernel<<<SCAN_N / SCAN_BS, 256, 0, stream>>>(ghist, bsums);
        scan2_kernel<<<1, 1024, 0, stream>>>(bsums, SCAN_N / SCAN_BS);
        scatter_kernel<<<NBLK, 256, 0, stream>>>(shifts, src, dst, bch, ghist, bsums,
                                                 recs, E, chunk);
        accum_kernel<<<B * NQ * PPB, 256, 0, stream>>>(recs, pos4, ghist, bsums,
                                                       partials, E, N, PPB);
        final_kernel<<<(BN + 255) / 256, 256, 0, stream>>>(partials, basis, raw,
                                                           (float*)d_out, BN, N, PPB);
    } else {
        // fallback: device-scope atomics
        float* pos  = (float*)d_ws;
        float* cart = pos + (size_t)BN * 3;
        float* rcp  = cart + (size_t)BN * 3;
        hipMemsetAsync(cart, 0, (size_t)BN * 3 * sizeof(float), stream);
        pos3_kernel<<<(BN + 255) / 256, 256, 0, stream>>>(rel, basis, pos, BN, N);
        inv_kernel<<<1, 64, 0, stream>>>(basis, rcp, B);
        edge_kernel_dev<<<(E + 255) / 256, 256, 0, stream>>>(pos, shifts, src, dst, bch,
                                                             cart, E, N);
        out_kernel<<<(BN + 255) / 256, 256, 0, stream>>>(cart, rcp, raw,
                                                         (float*)d_out, BN, N);
    }
}